// Round 7
// baseline (157.172 us; speedup 1.0000x reference)
//
#include <hip/hip_runtime.h>

#define B_SZ 8192
#define C_SZ 1024
#define NCLS 100
#define INV_T 0.25f
#define NTRI 21              // nt<=6 strips -> <=21 tri-tiles (m<=192: 12 sigma)
#define VITEMS (NCLS * NTRI) // 2100 virtual items, one block each
#define RSTR 17              // uint4 per LDS row (16 + 1 pad: conflict-free b128)

typedef unsigned int uint32;

using bf16x8 = __attribute__((ext_vector_type(8))) short;
using f32x16 = __attribute__((ext_vector_type(16))) float;

// tri-tile idx -> (ti, tj), ti <= tj, grouped by tj; valid iff idx < nt*(nt+1)/2
__device__ __constant__ char TI_OF[NTRI] = {
    0, 0,1, 0,1,2, 0,1,2,3, 0,1,2,3,4, 0,1,2,3,4,5};
__device__ __constant__ char TJ_OF[NTRI] = {
    0, 1,1, 2,2,2, 3,3,3,3, 4,4,4,4,4, 5,5,5,5,5,5};

// round-to-nearest-even fp32 -> bf16 (inputs positive, finite)
__device__ __forceinline__ unsigned short f2bf(float f) {
    uint32 u = __float_as_uint(f);
    u = u + 0x7fffu + ((u >> 16) & 1u);
    return (unsigned short)(u >> 16);
}

__global__ __launch_bounds__(128) void init_kernel(int* meta) {
    meta[threadIdx.x] = 0;   // counts[0..99], accum, done
}

// One block per row: softmax(x/T)+1e-8 -> bf16 probs; t[row]=mean(p log p);
// tid 0 appends the row to its label bucket.
__global__ __launch_bounds__(256) void softmax_bucket_kernel(
        const float* __restrict__ x, const int* __restrict__ target,
        uint32* __restrict__ probs_bf, float* __restrict__ t,
        int* __restrict__ counts, int* __restrict__ lists) {
    int row = blockIdx.x;
    int tid = threadIdx.x;

    if (tid == 0) {
        int lbl = target[row];
        int slot = atomicAdd(&counts[lbl], 1);
        lists[lbl * B_SZ + slot] = row;
    }

    const float4* xr = (const float4*)(x + (size_t)row * C_SZ);
    float4 v = xr[tid];
    v.x *= INV_T; v.y *= INV_T; v.z *= INV_T; v.w *= INV_T;

    __shared__ float red[12];
    int wid = tid >> 6;

    float m = fmaxf(fmaxf(v.x, v.y), fmaxf(v.z, v.w));
    #pragma unroll
    for (int o = 32; o >= 1; o >>= 1) m = fmaxf(m, __shfl_xor(m, o, 64));
    if ((tid & 63) == 0) red[wid] = m;
    __syncthreads();
    m = fmaxf(fmaxf(red[0], red[1]), fmaxf(red[2], red[3]));

    float4 e;
    e.x = __expf(v.x - m); e.y = __expf(v.y - m);
    e.z = __expf(v.z - m); e.w = __expf(v.w - m);
    float s = (e.x + e.y) + (e.z + e.w);
    #pragma unroll
    for (int o = 32; o >= 1; o >>= 1) s += __shfl_xor(s, o, 64);
    if ((tid & 63) == 0) red[4 + wid] = s;
    __syncthreads();
    float Z = (red[4] + red[5]) + (red[6] + red[7]);
    float rZ = 1.0f / Z;

    float4 p;
    p.x = e.x * rZ + 1e-8f; p.y = e.y * rZ + 1e-8f;
    p.z = e.z * rZ + 1e-8f; p.w = e.w * rZ + 1e-8f;

    uint2 packed;
    packed.x = ((uint32)f2bf(p.y) << 16) | (uint32)f2bf(p.x);
    packed.y = ((uint32)f2bf(p.w) << 16) | (uint32)f2bf(p.z);
    ((uint2*)(probs_bf + (size_t)row * (C_SZ / 2)))[tid] = packed;

    float pl = p.x * __logf(p.x) + p.y * __logf(p.y) +
               p.z * __logf(p.z) + p.w * __logf(p.w);
    #pragma unroll
    for (int o = 32; o >= 1; o >>= 1) pl += __shfl_xor(pl, o, 64);
    if ((tid & 63) == 0) red[8 + wid] = pl;
    __syncthreads();
    if (tid == 0)
        t[row] = ((red[8] + red[9]) + (red[10] + red[11])) * (1.0f / C_SZ);
}

// ONE 64-THREAD BLOCK PER VIRTUAL TRI-TILE (R2's proven shape + tri symmetry).
// Staging: per 128-col chunk, strips copied to LDS via compile-time-unrolled
// 16B loads (16 in flight); rids precomputed in registers via shuffle.
// Diagonal tiles stage one strip and use mfma(a,a) (half loads + half ds_reads).
// LDS row stride 17 uint4 -> conflict-free ds_write_b128 / ds_read_b128.
// mfma_f32_32x32x16_bf16 A/B frag: row=lane&31, kbase=(lane>>5)*8 (16B/lane).
// D: col=lane&31, row=(reg&3)+8*(reg>>2)+4*(lane>>5).
// Off-diag tile adds (t_j-c)^2 + (t_i-c)^2 (Gram symmetry). Last ticket
// publishes out[0].
__global__ __launch_bounds__(64) void pair_kernel(
        const char* __restrict__ probs, const float* __restrict__ t,
        const int* __restrict__ counts, const int* __restrict__ lists,
        float* __restrict__ accum, int* __restrict__ done,
        float* __restrict__ out) {
    __shared__ uint4 tile[64 * RSTR];    // 17 KB: 2 strips x 32 rows

    const int tid = threadIdx.x;
    const int v = blockIdx.x;
    const int k = v / NTRI;              // compile-time magic-mul
    const int r = v - k * NTRI;
    const int m = counts[k];
    const int nt = (m + 31) >> 5;
    const int tj = TJ_OF[r];
    const int ti = TI_OF[r];

    float total = 0.0f;

    if (tj < nt) {
        const bool diag = (ti == tj);
        const int lane5 = tid & 31;
        const int half = tid >> 5;

        // lanes 0..31 own A-strip rows, 32..63 own B-strip rows
        int rowidx = (tid < 32 ? ti : tj) * 32 + lane5;
        int w = rowidx < m ? rowidx : m - 1;         // clamp; masked in epilogue
        int rowrid = lists[k * B_SZ + w];
        float tv = t[rowrid];

        // per-thread staging byte-offsets, fixed across chunks
        int off[16];
        #pragma unroll
        for (int s = 0; s < 16; s++)
            off[s] = __shfl(rowrid, s * 4 + (tid >> 4), 64) * (C_SZ * 2);
        const int q = tid & 15;

        f32x16 acc = {};
        if (diag) {
            #pragma unroll 1
            for (int kc = 0; kc < 8; kc++) {
                #pragma unroll
                for (int s = 0; s < 8; s++) {
                    int rl = s * 4 + (tid >> 4);
                    uint4 vv = *(const uint4*)(probs + off[s] + kc * 256 + q * 16);
                    tile[rl * RSTR + q] = vv;
                }
                __syncthreads();
                #pragma unroll
                for (int kk = 0; kk < 8; kk++) {
                    bf16x8 a = *(const bf16x8*)&tile[lane5 * RSTR + kk * 2 + half];
                    acc = __builtin_amdgcn_mfma_f32_32x32x16_bf16(a, a, acc, 0, 0, 0);
                }
                __syncthreads();
            }
        } else {
            #pragma unroll 1
            for (int kc = 0; kc < 8; kc++) {
                #pragma unroll
                for (int s = 0; s < 16; s++) {
                    int rl = s * 4 + (tid >> 4);
                    uint4 vv = *(const uint4*)(probs + off[s] + kc * 256 + q * 16);
                    tile[rl * RSTR + q] = vv;
                }
                __syncthreads();
                #pragma unroll
                for (int kk = 0; kk < 8; kk++) {
                    bf16x8 a = *(const bf16x8*)&tile[lane5 * RSTR + kk * 2 + half];
                    bf16x8 b = *(const bf16x8*)&tile[(32 + lane5) * RSTR + kk * 2 + half];
                    acc = __builtin_amdgcn_mfma_f32_32x32x16_bf16(a, b, acc, 0, 0, 0);
                }
                __syncthreads();
            }
        }

        // epilogue
        const float invC = 1.0f / C_SZ;
        float tB = __shfl(tv, 32 + lane5, 64);       // t of B-strip row lane5
        int jl = tj * 32 + lane5;
        bool jv = jl < m;
        #pragma unroll
        for (int g = 0; g < 16; g++) {
            int rowloc = (g & 3) + 8 * (g >> 2) + 4 * half;
            float tA = __shfl(tv, rowloc, 64);       // t of A-strip row rowloc
            int il = ti * 32 + rowloc;
            if (jv && il < m) {
                float c = acc[g] * invC;
                if (diag) {
                    if (il != jl) { float d = tB - c; total += d * d; }
                } else {
                    float d1 = tB - c;
                    float d2 = tA - c;
                    total += d1 * d1 + d2 * d2;
                }
            }
        }
    }

    #pragma unroll
    for (int o = 32; o >= 1; o >>= 1) total += __shfl_xor(total, o, 64);
    if (tid == 0) {
        if (total != 0.0f) atomicAdd(accum, total);
        __threadfence();
        int ticket = atomicAdd(done, 1);
        if (ticket == VITEMS - 1) {
            float a = atomicAdd(accum, 0.0f);        // device-scope coherent read
            out[0] = a * (1.0f / B_SZ);
        }
    }
}

extern "C" void kernel_launch(void* const* d_in, const int* in_sizes, int n_in,
                              void* d_out, int out_size, void* d_ws, size_t ws_size,
                              hipStream_t stream) {
    const float* x = (const float*)d_in[0];
    const int* target = (const int*)d_in[1];
    float* out = (float*)d_out;

    char* ws = (char*)d_ws;
    uint32* probs_bf = (uint32*)ws;                                 // 16 MB
    char* p = ws + (size_t)B_SZ * C_SZ * 2;
    float* t = (float*)p;        p += B_SZ * 4;                     // 32 KB
    int* meta = (int*)p;         p += 128 * 4;                      // counts+accum+done
    int* counts = meta;
    float* accum = (float*)(meta + 100);
    int* done = meta + 101;
    int* lists = (int*)p;                                           // 3.2 MB

    init_kernel<<<1, 128, 0, stream>>>(meta);
    softmax_bucket_kernel<<<B_SZ, 256, 0, stream>>>(x, target, probs_bf, t,
                                                    counts, lists);
    pair_kernel<<<VITEMS, 64, 0, stream>>>((const char*)probs_bf, t, counts, lists,
                                           accum, done, out);
}